// Round 8
// baseline (733.296 us; speedup 1.0000x reference)
//
#include <hip/hip_runtime.h>
#include <hip/hip_bf16.h>

#define DIM 384
#define DI 768
#define S_LEN 1024
#define NB 32
#define M_ROWS (NB * S_LEN)   // 32768
#define MLP_DIM 1536
#define CHUNKS 32
#define CLEN (S_LEN / CHUNKS)  // 32

typedef __bf16 bf16x8 __attribute__((ext_vector_type(8)));
typedef float f32x4 __attribute__((ext_vector_type(4)));

#define GLOBAL_AS __attribute__((address_space(1)))
#define LDS_AS __attribute__((address_space(3)))

// ---------------- LayerNorm: one wave per row of 384 ----------------
template <typename OutT>
__global__ __launch_bounds__(256) void ln_kernel(const float* __restrict__ x,
                                                 const float* __restrict__ gamma,
                                                 const float* __restrict__ beta,
                                                 OutT* __restrict__ out) {
    int row = blockIdx.x * 4 + (threadIdx.x >> 6);
    int lane = threadIdx.x & 63;
    const float* xr = x + (size_t)row * DIM;
    float v[6];
    float s = 0.f, sq = 0.f;
#pragma unroll
    for (int i = 0; i < 6; ++i) {
        v[i] = xr[lane + i * 64];
        s += v[i];
        sq += v[i] * v[i];
    }
#pragma unroll
    for (int off = 32; off > 0; off >>= 1) {
        s += __shfl_down(s, off);
        sq += __shfl_down(sq, off);
    }
    s = __shfl(s, 0);
    sq = __shfl(sq, 0);
    float mean = s * (1.f / DIM);
    float var = sq * (1.f / DIM) - mean * mean;
    float rstd = rsqrtf(var + 1e-5f);
    OutT* orow = out + (size_t)row * DIM;
#pragma unroll
    for (int i = 0; i < 6; ++i) {
        int c = lane + i * 64;
        float y = (v[i] - mean) * rstd * gamma[c] + beta[c];
        if constexpr (sizeof(OutT) == 2)
            orow[c] = __float2bfloat16(y);
        else
            orow[c] = y;
    }
}

// ------- Depthwise 3x3 conv, vectorized: each thread does 8 consecutive channels -------
__global__ __launch_bounds__(256) void dwconv_kernel(const __hip_bfloat16* __restrict__ xn,
                                                     const float* __restrict__ w,
                                                     const float* __restrict__ b,
                                                     __hip_bfloat16* __restrict__ xs) {
    const int CB = DIM / 8;  // 48 channel-blocks per position
    size_t tid = (size_t)blockIdx.x * 256 + threadIdx.x;
    int cb = (int)(tid % CB);
    int s = (int)((tid / CB) % S_LEN);
    int n = (int)(tid / ((size_t)CB * S_LEN));
    int c = cb * 8;
    int h0 = s >> 5, w0 = s & 31;

    float wv[72];
    {
        const float4* wp = (const float4*)(w + (size_t)c * 9);
#pragma unroll
        for (int i = 0; i < 18; ++i) ((float4*)wv)[i] = wp[i];
    }
    float acc[8];
    {
        const float4 b0 = *(const float4*)&b[c];
        const float4 b1 = *(const float4*)&b[c + 4];
        acc[0] = b0.x; acc[1] = b0.y; acc[2] = b0.z; acc[3] = b0.w;
        acc[4] = b1.x; acc[5] = b1.y; acc[6] = b1.z; acc[7] = b1.w;
    }

    const __hip_bfloat16* base = xn + (size_t)n * S_LEN * DIM + c;
#pragma unroll
    for (int kh = 0; kh < 3; ++kh) {
        int hh = h0 + kh - 1;
        if (hh < 0 || hh > 31) continue;
#pragma unroll
        for (int kw = 0; kw < 3; ++kw) {
            int ww = w0 + kw - 1;
            if (ww < 0 || ww > 31) continue;
            bf16x8 xv = *(const bf16x8*)&base[(size_t)(hh * 32 + ww) * DIM];
#pragma unroll
            for (int e = 0; e < 8; ++e)
                acc[e] += (float)xv[e] * wv[e * 9 + kh * 3 + kw];
        }
    }
    bf16x8 ov;
#pragma unroll
    for (int e = 0; e < 8; ++e) ov[e] = (__bf16)acc[e];
    *(bf16x8*)&xs[tid * 8] = ov;
}

// ------- transpose + cast f32 -> bf16: out[c*ostride + ooff + r] = in[r*C + c] -------
__global__ __launch_bounds__(256) void transpose_bf16_kernel(const float* __restrict__ in,
                                                             __hip_bfloat16* __restrict__ out,
                                                             int R, int C, int ostride, int ooff) {
    int idx = blockIdx.x * 256 + threadIdx.x;
    if (idx >= R * C) return;
    int r = idx / C, c = idx % C;
    out[(size_t)c * ostride + ooff + r] = __float2bfloat16(in[idx]);
}

// ---------------- minGRU chunked scan ----------------
// vec2 (round 7): one thread owns a channel PAIR via 4B loads -- halves load-instruction
// count vs scalar while keeping 1536 blocks (6/CU, 24 waves/CU all-resident). Round-5
// lesson: vec8's 8x thread collapse (1.5 blocks/CU) lost 57us; vec2 keeps TLP.
__device__ __forceinline__ void gru_ab(float hid, float gate, float& a, float& bv) {
    float z = 1.f / (1.f + __expf(-gate));
    float gh = (hid >= 0.f) ? (hid + 0.5f) : (1.f / (1.f + __expf(-hid)));
    a = 1.f - z;
    bv = z * gh;
}

__global__ __launch_bounds__(256) void scan_part1(const __hip_bfloat16* __restrict__ hg,
                                                  float* __restrict__ summ, int rev) {
    const int CP = DI / 2;  // 384 channel pairs
    int tid = blockIdx.x * 256 + threadIdx.x;  // NB*CHUNKS*CP
    int cp = tid % CP;
    int j = (tid / CP) % CHUNKS;
    int b = tid / (CP * CHUNKS);
    int c = cp * 2;
    const __hip_bfloat16* base = hg + (size_t)b * S_LEN * (2 * DI);
    float A0 = 1.f, B0 = 0.f, A1 = 1.f, B1 = 0.f;
    for (int i = 0; i < CLEN; i += 8) {
        unsigned hidw[8], gatew[8];
#pragma unroll
        for (int q = 0; q < 8; ++q) {
            int pos = j * CLEN + i + q;
            int t = rev ? (S_LEN - 1 - pos) : pos;
            hidw[q] = *(const unsigned*)&base[(size_t)t * (2 * DI) + c];
            gatew[q] = *(const unsigned*)&base[(size_t)t * (2 * DI) + DI + c];
        }
#pragma unroll
        for (int q = 0; q < 8; ++q) {
            float a, bv;
            gru_ab(__uint_as_float(hidw[q] << 16), __uint_as_float(gatew[q] << 16), a, bv);
            A0 *= a; B0 = a * B0 + bv;
            gru_ab(__uint_as_float(hidw[q] & 0xffff0000u),
                   __uint_as_float(gatew[q] & 0xffff0000u), a, bv);
            A1 *= a; B1 = a * B1 + bv;
        }
    }
    size_t idx = (size_t)(j * NB + b) * DI + c;
    float* sB = summ + (size_t)CHUNKS * NB * DI;
    *(float2*)&summ[idx] = make_float2(A0, A1);
    *(float2*)&sB[idx] = make_float2(B0, B1);
}

// part2: writes h with row stride `ostride`; may alias hg in-place (per-q 4B load happens
// before the 4B store of the same location; cross-thread addresses disjoint).
__global__ __launch_bounds__(256) void scan_part2(const __hip_bfloat16* __restrict__ hg,
                                                  const float* __restrict__ summ,
                                                  __hip_bfloat16* __restrict__ ho, int rev,
                                                  int ostride) {
    const int CP = DI / 2;
    int tid = blockIdx.x * 256 + threadIdx.x;
    int cp = tid % CP;
    int j = (tid / CP) % CHUNKS;
    int b = tid / (CP * CHUNKS);
    int c = cp * 2;
    const float* sB = summ + (size_t)CHUNKS * NB * DI;
    float h0 = 0.f, h1 = 0.f;
    for (int jp = 0; jp < j; ++jp) {
        size_t idx = (size_t)(jp * NB + b) * DI + c;
        float2 a2 = *(const float2*)&summ[idx];
        float2 b2 = *(const float2*)&sB[idx];
        h0 = a2.x * h0 + b2.x;
        h1 = a2.y * h1 + b2.y;
    }
    const __hip_bfloat16* base = hg + (size_t)b * S_LEN * (2 * DI);
    __hip_bfloat16* hob = ho + (size_t)b * S_LEN * ostride;
    for (int i = 0; i < CLEN; i += 8) {
        unsigned hidw[8], gatew[8];
        int tt[8];
#pragma unroll
        for (int q = 0; q < 8; ++q) {
            int pos = j * CLEN + i + q;
            int t = rev ? (S_LEN - 1 - pos) : pos;
            tt[q] = t;
            hidw[q] = *(const unsigned*)&base[(size_t)t * (2 * DI) + c];
            gatew[q] = *(const unsigned*)&base[(size_t)t * (2 * DI) + DI + c];
        }
#pragma unroll
        for (int q = 0; q < 8; ++q) {
            float a, bv;
            gru_ab(__uint_as_float(hidw[q] << 16), __uint_as_float(gatew[q] << 16), a, bv);
            h0 = a * h0 + bv;
            gru_ab(__uint_as_float(hidw[q] & 0xffff0000u),
                   __uint_as_float(gatew[q] & 0xffff0000u), a, bv);
            h1 = a * h1 + bv;
            union { __hip_bfloat16 hh[2]; unsigned u; } o;
            o.hh[0] = __float2bfloat16(h0);
            o.hh[1] = __float2bfloat16(h1);
            *(unsigned*)&hob[(size_t)tt[q] * ostride + c] = o.u;
        }
    }
}

// ------- bf16 MFMA GEMM, persistent multi-tile (round 7) -------
// r3 128x128 body (93us measured) kept byte-for-byte; each block now processes `mtiles`
// M-tiles sequentially (grid.y = M/128/mtiles). With mtiles=4: 768 blocks = exactly 3/CU
// all-resident, and the K-pipeline NEVER drains across tile boundaries: stage(gk+2)
// rolls into the next tile's kt=0/1; epilogue's 16 int2 stores are issued and left in
// flight (store data in packed regs -> acc reinit is hazard-free).
// vmcnt accounting (4 loads/stage, 16 stores/epilogue; bias hoisted pre-loop so epilogue
// VMEM = stores only):
//   top of iter gk needs stage(gk)'s 4 loads retired. Newer ops:
//     normal iters: stage(gk+1) -> vmcnt(4)
//     first 2 iters of a non-first tile: stage(gk+1) + 16 stores -> vmcnt(20)
//     (3rd iter's vmcnt(4) also drains the stores -- ~3k cycles old, complete)
//     last iter overall: vmcnt(0)
// WAR unchanged: stage(gk+2) overwrites buf[(gk-1)%3]; barrier release implies all
// waves' buf[gk-1] reads drained. mtiles=1 path is bit-identical to r3 (outF/add GEMMs).
// XCD-chunked swizzle on persistent ids: XCD owns contiguous tile range; the 12 bx of a
// pby share A-panels per generation (<=1MB hot in its L2).
__global__ __launch_bounds__(256) void gemm_bt(const __hip_bfloat16* __restrict__ A1, int lda1,
                                               const __hip_bfloat16* __restrict__ A2, int lda2,
                                               int ksplit,
                                               const __hip_bfloat16* __restrict__ Bt,
                                               int M, int N, int K, int mtiles,
                                               __hip_bfloat16* __restrict__ outH,
                                               float* __restrict__ outF,
                                               const float* __restrict__ bias,
                                               const float* __restrict__ add,
                                               int act) {
    __shared__ __align__(16) __hip_bfloat16 sA[3][128 * 32];
    __shared__ __align__(16) __hip_bfloat16 sB[3][128 * 32];
    int t = threadIdx.x;

    int nwg = gridDim.x * gridDim.y;
    int pid = blockIdx.y * gridDim.x + blockIdx.x;
    int cpx = nwg >> 3;  // all gemm grids here are divisible by 8 (bijective)
    int tile = (pid & 7) * cpx + (pid >> 3);
    int bx = tile % gridDim.x;
    int pby = tile / gridDim.x;
    int n0 = bx * 128;

    int wave = t >> 6, lane = t & 63;
    int wm = (wave >> 1) << 6, wn = (wave & 1) << 6;
    int quad = lane >> 4, lr = lane & 15;

    f32x4 acc[4][4];
#pragma unroll
    for (int i = 0; i < 4; ++i)
#pragma unroll
        for (int j = 0; j < 4; ++j)
#pragma unroll
            for (int e = 0; e < 4; ++e) acc[i][j][e] = 0.f;

    int ch0 = wave * 128 + lane;
    int ch1 = wave * 128 + 64 + lane;
    // stage-side T2 swizzle: thread covering LDS (row r, slot s=ch&3) fetches global
    // slot s^f(r), f(r)=(r>>1)&3 (verified: SQ_LDS_BANK_CONFLICT = 0)
    int r0 = ch0 >> 2, g0 = (((ch0 & 3) ^ ((r0 >> 1) & 3)) * 8);
    int r1 = ch1 >> 2, g1 = (((ch1 & 3) ^ ((r1 >> 1) & 3)) * 8);
    // read-side swizzle offset (loop-invariant): element offset (quad ^ (lr>>1)&3)*8
    int qx = (quad ^ ((lr >> 1) & 3)) * 8;

    const int KT = K >> 5;
    const int total = KT * mtiles;

    // hoist bias (loop-invariant): keeps epilogue VMEM = stores only, which the
    // cross-tile vmcnt(20) accounting requires.
    float4 bias4[4];
    if (bias) {
#pragma unroll
        for (int ni = 0; ni < 4; ++ni)
            bias4[ni] = *(const float4*)&bias[n0 + wn + ni * 16 + quad * 4];
    }

    auto stage = [&](int m0s, int k0, int bi) {
        const __hip_bfloat16* Ab;
        int ldx, kk;
        if (k0 < ksplit) { Ab = A1; ldx = lda1; kk = k0; }
        else             { Ab = A2; ldx = lda2; kk = k0 - ksplit; }
        __builtin_amdgcn_global_load_lds((const GLOBAL_AS void*)(Ab + (size_t)(m0s + r0) * ldx + kk + g0),
                                         (LDS_AS void*)&sA[bi][ch0 * 8], 16, 0, 0);
        __builtin_amdgcn_global_load_lds((const GLOBAL_AS void*)(Ab + (size_t)(m0s + r1) * ldx + kk + g1),
                                         (LDS_AS void*)&sA[bi][ch1 * 8], 16, 0, 0);
        __builtin_amdgcn_global_load_lds((const GLOBAL_AS void*)(Bt + (size_t)(n0 + r0) * K + k0 + g0),
                                         (LDS_AS void*)&sB[bi][ch0 * 8], 16, 0, 0);
        __builtin_amdgcn_global_load_lds((const GLOBAL_AS void*)(Bt + (size_t)(n0 + r1) * K + k0 + g1),
                                         (LDS_AS void*)&sB[bi][ch1 * 8], 16, 0, 0);
    };

    // stage cursor (kt, mtile, buffer) advancing over the global pipeline index
    int s_kt = 0, s_mt = 0, s_bi = 0;
    auto sadv = [&]() {
        if (++s_kt == KT) { s_kt = 0; ++s_mt; }
        if (++s_bi == 3) s_bi = 0;
    };

    stage((pby + s_mt * gridDim.y) * 128, s_kt << 5, s_bi);
    sadv();
    stage((pby + s_mt * gridDim.y) * 128, s_kt << 5, s_bi);
    sadv();

    int bi = 0;
    for (int g = 0; g < mtiles; ++g) {
        int m0 = (pby + g * gridDim.y) * 128;
        for (int kt = 0; kt < KT; ++kt) {
            int gk = g * KT + kt;
            if (gk + 1 >= total) {
                asm volatile("s_waitcnt vmcnt(0)" ::: "memory");
            } else if (g > 0 && kt < 2) {
                asm volatile("s_waitcnt vmcnt(20)" ::: "memory");  // 4 loads + 16 stores newer
            } else {
                asm volatile("s_waitcnt vmcnt(4)" ::: "memory");
            }
            __builtin_amdgcn_s_barrier();  // buf[gk%3] ready; all buf[gk-1] reads drained
            asm volatile("" ::: "memory"); // pin: no memory op hoists above the barrier
            bf16x8 af[4], bfr[4];
#pragma unroll
            for (int mi = 0; mi < 4; ++mi)
                af[mi] = *(const bf16x8*)&sA[bi][(wm + mi * 16 + lr) * 32 + qx];
#pragma unroll
            for (int ni = 0; ni < 4; ++ni)
                bfr[ni] = *(const bf16x8*)&sB[bi][(wn + ni * 16 + lr) * 32 + qx];
            if (gk + 2 < total) {
                stage((pby + s_mt * gridDim.y) * 128, s_kt << 5, s_bi);
                sadv();
            }
#pragma unroll
            for (int mi = 0; mi < 4; ++mi)
#pragma unroll
                for (int ni = 0; ni < 4; ++ni)
                    acc[mi][ni] = __builtin_amdgcn_mfma_f32_16x16x32_bf16(bfr[ni], af[mi], acc[mi][ni], 0, 0, 0);
            if (++bi == 3) bi = 0;
        }

        // epilogue for tile g: 16 stores (int2 / float4), data packed into fresh regs so
        // the stores can stay in flight across the next tile's iterations.
#pragma unroll
        for (int mi = 0; mi < 4; ++mi) {
            int row = m0 + wm + mi * 16 + lr;
#pragma unroll
            for (int ni = 0; ni < 4; ++ni) {
                int col = n0 + wn + ni * 16 + quad * 4;
                size_t idx = (size_t)row * N + col;
                f32x4 v = acc[mi][ni];
                if (bias) {
                    v[0] += bias4[ni].x; v[1] += bias4[ni].y;
                    v[2] += bias4[ni].z; v[3] += bias4[ni].w;
                }
                if (act == 1) {
#pragma unroll
                    for (int e = 0; e < 4; ++e) {
                        // tanh-approx gelu (max dev ~3e-4; vanishes through next GEMM)
                        float xv = v[e];
                        float u = 0.7978845608f * (xv + 0.044715f * xv * xv * xv);
                        float ex = __expf(2.f * u);
                        float th = (ex - 1.f) / (ex + 1.f);
                        v[e] = 0.5f * xv * (1.f + th);
                    }
                }
                if (add) {
                    const float4 a4 = *(const float4*)&add[idx];
                    v[0] += a4.x; v[1] += a4.y; v[2] += a4.z; v[3] += a4.w;
                }
                if (outH) {
                    union { __hip_bfloat16 h[4]; int2 i2; } u;
                    u.h[0] = __float2bfloat16(v[0]);
                    u.h[1] = __float2bfloat16(v[1]);
                    u.h[2] = __float2bfloat16(v[2]);
                    u.h[3] = __float2bfloat16(v[3]);
                    *(int2*)&outH[idx] = u.i2;
                } else {
                    *(float4*)&outF[idx] = make_float4(v[0], v[1], v[2], v[3]);
                }
            }
        }
        if (g + 1 < mtiles) {
#pragma unroll
            for (int i = 0; i < 4; ++i)
#pragma unroll
                for (int j = 0; j < 4; ++j)
#pragma unroll
                    for (int e = 0; e < 4; ++e) acc[i][j][e] = 0.f;
        }
    }
}

extern "C" void kernel_launch(void* const* d_in, const int* in_sizes, int n_in,
                              void* d_out, int out_size, void* d_ws, size_t ws_size,
                              hipStream_t stream) {
    const float* x = (const float*)d_in[0];
    const float* gamma1 = (const float*)d_in[1];
    const float* beta1 = (const float*)d_in[2];
    const float* dwc_w = (const float*)d_in[3];
    const float* dwc_b = (const float*)d_in[4];
    const float* gru1_w = (const float*)d_in[5];
    const float* gru1_o = (const float*)d_in[6];
    const float* gru2_w = (const float*)d_in[7];
    const float* gru2_o = (const float*)d_in[8];
    const float* gamma2 = (const float*)d_in[9];
    const float* beta2 = (const float*)d_in[10];
    const float* p1_w = (const float*)d_in[11];
    const float* p1_b = (const float*)d_in[12];
    const float* p2_w = (const float*)d_in[13];
    const float* p2_b = (const float*)d_in[14];
    float* out = (float*)d_out;

    char* ws = (char*)d_ws;
    size_t off = 0;
    auto alloc = [&](size_t b) {
        char* p = ws + off;
        off += (b + 255) & ~(size_t)255;
        return p;
    };
    const size_t M = M_ROWS;
    // ws total ~188 MB
    __hip_bfloat16* hg = (__hip_bfloat16*)alloc(M * 2 * DI * 2);    // 100.7 MB; h2 in-place; later t1
    __hip_bfloat16* hbuf = (__hip_bfloat16*)alloc(M * DI * 2);      // 50.3 MB: LN1-bf16 out, then h1
    __hip_bfloat16* xs = (__hip_bfloat16*)alloc(M * DIM * 2);       // 25.2 MB; later yn
    float* summ = (float*)alloc((size_t)2 * CHUNKS * NB * DI * 4);  // 6.3 MB
    __hip_bfloat16* w1T = (__hip_bfloat16*)alloc((size_t)DIM * 2 * DI * 2);
    __hip_bfloat16* w2T = (__hip_bfloat16*)alloc((size_t)DIM * 2 * DI * 2);
    __hip_bfloat16* ocT = (__hip_bfloat16*)alloc((size_t)DIM * 2 * DI * 2);  // 384 x 1536 = [o1;o2]^T
    __hip_bfloat16* p1T = (__hip_bfloat16*)alloc((size_t)DIM * MLP_DIM * 2);
    __hip_bfloat16* p2T = (__hip_bfloat16*)alloc((size_t)MLP_DIM * DIM * 2);
    __hip_bfloat16* xnb = hbuf;           // LN1 out (bf16); dead after dwconv, before scan1
    float* y = (float*)d_out;             // post-GRU residual; same-idx RMW only
    __hip_bfloat16* yn = xs;              // LN2 out; xs dead after GRU2 input GEMM
    __hip_bfloat16* t1 = hg;              // MLP hidden; hg dead after scan2

    auto tgrid = [](int n) { return dim3((n + 255) / 256); };
    transpose_bf16_kernel<<<tgrid(DIM * 2 * DI), 256, 0, stream>>>(gru1_w, w1T, DIM, 2 * DI, DIM, 0);
    transpose_bf16_kernel<<<tgrid(DIM * 2 * DI), 256, 0, stream>>>(gru2_w, w2T, DIM, 2 * DI, DIM, 0);
    transpose_bf16_kernel<<<tgrid(DI * DIM), 256, 0, stream>>>(gru1_o, ocT, DI, DIM, 2 * DI, 0);
    transpose_bf16_kernel<<<tgrid(DI * DIM), 256, 0, stream>>>(gru2_o, ocT, DI, DIM, 2 * DI, DI);
    transpose_bf16_kernel<<<tgrid(DIM * MLP_DIM), 256, 0, stream>>>(p1_w, p1T, DIM, MLP_DIM, DIM, 0);
    transpose_bf16_kernel<<<tgrid(MLP_DIM * DIM), 256, 0, stream>>>(p2_w, p2T, MLP_DIM, DIM, MLP_DIM, 0);

    ln_kernel<__hip_bfloat16><<<dim3(M / 4), 256, 0, stream>>>(x, gamma1, beta1, xnb);
    dwconv_kernel<<<dim3((int)((M * DIM / 8) / 256)), 256, 0, stream>>>(xnb, dwc_w, dwc_b, xs);

    const int scan_blocks = NB * CHUNKS * (DI / 2) / 256;  // 1536
    // GRU1: hg = xs @ w1; scan fwd -> h1 (hbuf, stride DI)
    gemm_bt<<<dim3(2 * DI / 128, M / 128 / 4), 256, 0, stream>>>(xs, DIM, xs, DIM, DIM, w1T, M, 2 * DI, DIM, 4,
                                                                 hg, nullptr, nullptr, nullptr, 0);
    scan_part1<<<dim3(scan_blocks), 256, 0, stream>>>(hg, summ, 0);
    scan_part2<<<dim3(scan_blocks), 256, 0, stream>>>(hg, summ, hbuf, 0, DI);
    // GRU2: hg = xs @ w2; scan bwd -> h2 in-place into hg[:, 0:DI] (stride 2*DI)
    gemm_bt<<<dim3(2 * DI / 128, M / 128 / 4), 256, 0, stream>>>(xs, DIM, xs, DIM, DIM, w2T, M, 2 * DI, DIM, 4,
                                                                 hg, nullptr, nullptr, nullptr, 0);
    scan_part1<<<dim3(scan_blocks), 256, 0, stream>>>(hg, summ, 1);
    scan_part2<<<dim3(scan_blocks), 256, 0, stream>>>(hg, summ, hg, 1, 2 * DI);

    // merged GRU out: y = [h1 | h2] @ [o1;o2] + x   (K=1536; outF+add -> mtiles=1)
    gemm_bt<<<dim3(DIM / 128, M / 128), 256, 0, stream>>>(hbuf, DI, hg, 2 * DI, DI, ocT, M, DIM, 2 * DI, 1,
                                                          nullptr, y, nullptr, x, 0);

    // LN2 + MLP
    ln_kernel<__hip_bfloat16><<<dim3(M / 4), 256, 0, stream>>>(y, gamma2, beta2, yn);
    gemm_bt<<<dim3(MLP_DIM / 128, M / 128 / 4), 256, 0, stream>>>(yn, DIM, yn, DIM, DIM, p1T, M, MLP_DIM, DIM, 4,
                                                                  t1, nullptr, p1_b, nullptr, 1);
    gemm_bt<<<dim3(DIM / 128, M / 128), 256, 0, stream>>>(t1, MLP_DIM, t1, MLP_DIM, MLP_DIM, p2T, M, DIM, MLP_DIM, 1,
                                                          nullptr, out, p2_b, y, 0);
}

// Round 9
// 682.608 us; speedup vs baseline: 1.0743x; 1.0743x over previous
//
#include <hip/hip_runtime.h>
#include <hip/hip_bf16.h>

#define DIM 384
#define DI 768
#define S_LEN 1024
#define NB 32
#define M_ROWS (NB * S_LEN)   // 32768
#define MLP_DIM 1536
#define CHUNKS 32
#define CLEN (S_LEN / CHUNKS)  // 32

typedef __bf16 bf16x8 __attribute__((ext_vector_type(8)));
typedef float f32x4 __attribute__((ext_vector_type(4)));

#define GLOBAL_AS __attribute__((address_space(1)))
#define LDS_AS __attribute__((address_space(3)))

// ---------------- LayerNorm: one wave per row of 384 ----------------
template <typename OutT>
__global__ __launch_bounds__(256) void ln_kernel(const float* __restrict__ x,
                                                 const float* __restrict__ gamma,
                                                 const float* __restrict__ beta,
                                                 OutT* __restrict__ out) {
    int row = blockIdx.x * 4 + (threadIdx.x >> 6);
    int lane = threadIdx.x & 63;
    const float* xr = x + (size_t)row * DIM;
    float v[6];
    float s = 0.f, sq = 0.f;
#pragma unroll
    for (int i = 0; i < 6; ++i) {
        v[i] = xr[lane + i * 64];
        s += v[i];
        sq += v[i] * v[i];
    }
#pragma unroll
    for (int off = 32; off > 0; off >>= 1) {
        s += __shfl_down(s, off);
        sq += __shfl_down(sq, off);
    }
    s = __shfl(s, 0);
    sq = __shfl(sq, 0);
    float mean = s * (1.f / DIM);
    float var = sq * (1.f / DIM) - mean * mean;
    float rstd = rsqrtf(var + 1e-5f);
    OutT* orow = out + (size_t)row * DIM;
#pragma unroll
    for (int i = 0; i < 6; ++i) {
        int c = lane + i * 64;
        float y = (v[i] - mean) * rstd * gamma[c] + beta[c];
        if constexpr (sizeof(OutT) == 2)
            orow[c] = __float2bfloat16(y);
        else
            orow[c] = y;
    }
}

// ------- Depthwise 3x3 conv, vectorized: each thread does 8 consecutive channels -------
__global__ __launch_bounds__(256) void dwconv_kernel(const __hip_bfloat16* __restrict__ xn,
                                                     const float* __restrict__ w,
                                                     const float* __restrict__ b,
                                                     __hip_bfloat16* __restrict__ xs) {
    const int CB = DIM / 8;  // 48 channel-blocks per position
    size_t tid = (size_t)blockIdx.x * 256 + threadIdx.x;
    int cb = (int)(tid % CB);
    int s = (int)((tid / CB) % S_LEN);
    int n = (int)(tid / ((size_t)CB * S_LEN));
    int c = cb * 8;
    int h0 = s >> 5, w0 = s & 31;

    float wv[72];
    {
        const float4* wp = (const float4*)(w + (size_t)c * 9);
#pragma unroll
        for (int i = 0; i < 18; ++i) ((float4*)wv)[i] = wp[i];
    }
    float acc[8];
    {
        const float4 b0 = *(const float4*)&b[c];
        const float4 b1 = *(const float4*)&b[c + 4];
        acc[0] = b0.x; acc[1] = b0.y; acc[2] = b0.z; acc[3] = b0.w;
        acc[4] = b1.x; acc[5] = b1.y; acc[6] = b1.z; acc[7] = b1.w;
    }

    const __hip_bfloat16* base = xn + (size_t)n * S_LEN * DIM + c;
#pragma unroll
    for (int kh = 0; kh < 3; ++kh) {
        int hh = h0 + kh - 1;
        if (hh < 0 || hh > 31) continue;
#pragma unroll
        for (int kw = 0; kw < 3; ++kw) {
            int ww = w0 + kw - 1;
            if (ww < 0 || ww > 31) continue;
            bf16x8 xv = *(const bf16x8*)&base[(size_t)(hh * 32 + ww) * DIM];
#pragma unroll
            for (int e = 0; e < 8; ++e)
                acc[e] += (float)xv[e] * wv[e * 9 + kh * 3 + kw];
        }
    }
    bf16x8 ov;
#pragma unroll
    for (int e = 0; e < 8; ++e) ov[e] = (__bf16)acc[e];
    *(bf16x8*)&xs[tid * 8] = ov;
}

// ------- transpose + cast f32 -> bf16: out[c*ostride + ooff + r] = in[r*C + c] -------
__global__ __launch_bounds__(256) void transpose_bf16_kernel(const float* __restrict__ in,
                                                             __hip_bfloat16* __restrict__ out,
                                                             int R, int C, int ostride, int ooff) {
    int idx = blockIdx.x * 256 + threadIdx.x;
    if (idx >= R * C) return;
    int r = idx / C, c = idx % C;
    out[(size_t)c * ostride + ooff + r] = __float2bfloat16(in[idx]);
}

// ---------------- minGRU chunked scan (scalar form: high TLP, 3072 blocks) ----------------
// Rounds 5/8 lessons: vec8 (384 blocks) lost 57us, vec2 (1536 blocks) lost ~20us.
// The scan is a latency-bound dependent chain; thread-count IS the latency hiding.
__device__ __forceinline__ void gru_ab(float hid, float gate, float& a, float& bv) {
    float z = 1.f / (1.f + __expf(-gate));
    float gh = (hid >= 0.f) ? (hid + 0.5f) : (1.f / (1.f + __expf(-hid)));
    a = 1.f - z;
    bv = z * gh;
}

__global__ __launch_bounds__(256) void scan_part1(const __hip_bfloat16* __restrict__ hg,
                                                  float* __restrict__ summ, int rev) {
    int tid = blockIdx.x * 256 + threadIdx.x;  // NB*CHUNKS*DI
    int c = tid % DI;
    int j = (tid / DI) % CHUNKS;
    int b = tid / (DI * CHUNKS);
    const __hip_bfloat16* base = hg + (size_t)b * S_LEN * (2 * DI);
    float A = 1.f, Bv = 0.f;
    for (int i = 0; i < CLEN; i += 8) {
        float hid[8], gate[8];
#pragma unroll
        for (int q = 0; q < 8; ++q) {
            int pos = j * CLEN + i + q;
            int t = rev ? (S_LEN - 1 - pos) : pos;
            hid[q] = __bfloat162float(base[(size_t)t * (2 * DI) + c]);
            gate[q] = __bfloat162float(base[(size_t)t * (2 * DI) + DI + c]);
        }
#pragma unroll
        for (int q = 0; q < 8; ++q) {
            float a, bv;
            gru_ab(hid[q], gate[q], a, bv);
            A *= a;
            Bv = a * Bv + bv;
        }
    }
    int idx = (j * NB + b) * DI + c;
    summ[idx] = A;
    summ[(size_t)CHUNKS * NB * DI + idx] = Bv;
}

// part2: writes h with row stride `ostride`; may alias hg in-place (1:1 read-before-write)
__global__ __launch_bounds__(256) void scan_part2(const __hip_bfloat16* __restrict__ hg,
                                                  const float* __restrict__ summ,
                                                  __hip_bfloat16* __restrict__ ho, int rev,
                                                  int ostride) {
    int tid = blockIdx.x * 256 + threadIdx.x;
    int c = tid % DI;
    int j = (tid / DI) % CHUNKS;
    int b = tid / (DI * CHUNKS);
    const float* sB = summ + (size_t)CHUNKS * NB * DI;
    float h = 0.f;
    for (int jp = 0; jp < j; ++jp) {
        int idx = (jp * NB + b) * DI + c;
        h = summ[idx] * h + sB[idx];
    }
    const __hip_bfloat16* base = hg + (size_t)b * S_LEN * (2 * DI);
    __hip_bfloat16* hob = ho + (size_t)b * S_LEN * ostride;
    for (int i = 0; i < CLEN; i += 8) {
        float hid[8], gate[8];
        int tt[8];
#pragma unroll
        for (int q = 0; q < 8; ++q) {
            int pos = j * CLEN + i + q;
            int t = rev ? (S_LEN - 1 - pos) : pos;
            tt[q] = t;
            hid[q] = __bfloat162float(base[(size_t)t * (2 * DI) + c]);
            gate[q] = __bfloat162float(base[(size_t)t * (2 * DI) + DI + c]);
        }
#pragma unroll
        for (int q = 0; q < 8; ++q) {
            float a, bv;
            gru_ab(hid[q], gate[q], a, bv);
            h = a * h + bv;
            hob[(size_t)tt[q] * ostride + c] = __float2bfloat16(h);
        }
    }
}

// ------- bf16 MFMA GEMM: r3 schedule, 8-wave blocks (round 9) -------
// The r3 K-loop (93us, best measured) is kept EXACTLY: 3 LDS buffers, depth-2 prefetch,
// single barrier/iter, counted vmcnt. Change: 512 threads / 8 waves per 128x128 tile,
// per-wave 64x32 (acc 4x2 = 32 VGPR). LDS unchanged (48KB -> 3 blocks/CU), so waves/CU
// doubles: 12 -> 24 (6/SIMD). Rationale: occupancy was 29% and every TLP-raising change
// in this session won while every TLP-lowering change lost; the loop is latency-bound.
// __launch_bounds__(512,6) caps VGPR at 85 so all 3 blocks get wave slots.
// Staging: 512 threads <-> 512 16B chunks per buffer -> 1 A + 1 B load per thread;
// steady-state vmcnt(2) = retire tile kt's 2 loads, keep tile kt+1's 2 in flight.
// WAR: stage(kt+2) overwrites buf[(kt-1)%3]; barrier release implies all waves'
// buf[kt-1] reads drained. T2 swizzle unchanged: f(row)=(row>>1)&3 reduces to
// (lr>>1)&3 on reads (wm in {0,64}, wn in {0,32,64,96} are 0 mod 8). XCD swizzle kept.
__global__ __launch_bounds__(512, 6) void gemm_bt(const __hip_bfloat16* __restrict__ A1, int lda1,
                                                  const __hip_bfloat16* __restrict__ A2, int lda2,
                                                  int ksplit,
                                                  const __hip_bfloat16* __restrict__ Bt,
                                                  int M, int N, int K,
                                                  __hip_bfloat16* __restrict__ outH,
                                                  float* __restrict__ outF,
                                                  const float* __restrict__ bias,
                                                  const float* __restrict__ add,
                                                  int act) {
    __shared__ __align__(16) __hip_bfloat16 sA[3][128 * 32];
    __shared__ __align__(16) __hip_bfloat16 sB[3][128 * 32];
    int t = threadIdx.x;

    int nwg = gridDim.x * gridDim.y;
    int bid = blockIdx.y * gridDim.x + blockIdx.x;
    int cpx = nwg >> 3;  // all gemm grids here are divisible by 8 (bijective)
    int tile = (bid & 7) * cpx + (bid >> 3);
    int bx = tile % gridDim.x;
    int by = tile / gridDim.x;
    int n0 = bx * 128;
    int m0 = by * 128;

    int wave = t >> 6, lane = t & 63;
    int wm = (wave >> 2) << 6;  // 0 or 64
    int wn = (wave & 3) << 5;   // 0, 32, 64, 96
    int quad = lane >> 4, lr = lane & 15;

    f32x4 acc[4][2];
#pragma unroll
    for (int i = 0; i < 4; ++i)
#pragma unroll
        for (int j = 0; j < 2; ++j)
#pragma unroll
            for (int e = 0; e < 4; ++e) acc[i][j][e] = 0.f;

    // staging: each buffer = 512 16B chunks (128 rows x 4 slots); thread t owns chunk t.
    // T2 swizzle on the global source slot: LDS (row r, slot s) holds global slot s^f(r).
    int r0 = t >> 2, g0 = (((t & 3) ^ ((r0 >> 1) & 3)) * 8);
    // read-side swizzle offset (loop-invariant): element offset (quad ^ (lr>>1)&3)*8
    int qx = (quad ^ ((lr >> 1) & 3)) * 8;

    const int KT = K >> 5;  // #32-wide k-tiles (>= 12 for all calls)

    auto stage = [&](int kt) {
        int k0 = kt << 5;
        const __hip_bfloat16* Ab;
        int ldx, kk;
        if (k0 < ksplit) { Ab = A1; ldx = lda1; kk = k0; }
        else             { Ab = A2; ldx = lda2; kk = k0 - ksplit; }
        int bi = kt % 3;
        __builtin_amdgcn_global_load_lds((const GLOBAL_AS void*)(Ab + (size_t)(m0 + r0) * ldx + kk + g0),
                                         (LDS_AS void*)&sA[bi][t * 8], 16, 0, 0);
        __builtin_amdgcn_global_load_lds((const GLOBAL_AS void*)(Bt + (size_t)(n0 + r0) * K + k0 + g0),
                                         (LDS_AS void*)&sB[bi][t * 8], 16, 0, 0);
    };

    stage(0);
    stage(1);
    for (int kt = 0; kt < KT; ++kt) {
        // Retire tile kt's 2 loads (keep tile kt+1's 2 in flight - counted, never 0 mid-loop).
        if (kt + 1 < KT) {
            asm volatile("s_waitcnt vmcnt(2)" ::: "memory");
        } else {
            asm volatile("s_waitcnt vmcnt(0)" ::: "memory");
        }
        __builtin_amdgcn_s_barrier();  // buf[kt%3] ready; all buf[kt-1] reads drained
        asm volatile("" ::: "memory"); // pin: no memory op (stage) hoists above the barrier
        int bi = kt % 3;
        bf16x8 af[4], bfr[2];
#pragma unroll
        for (int mi = 0; mi < 4; ++mi)
            af[mi] = *(const bf16x8*)&sA[bi][(wm + mi * 16 + lr) * 32 + qx];
#pragma unroll
        for (int ni = 0; ni < 2; ++ni)
            bfr[ni] = *(const bf16x8*)&sB[bi][(wn + ni * 16 + lr) * 32 + qx];
        if (kt + 2 < KT) stage(kt + 2);  // issue under the lgkm shadow of the ds_reads
#pragma unroll
        for (int mi = 0; mi < 4; ++mi)
#pragma unroll
            for (int ni = 0; ni < 2; ++ni)
                acc[mi][ni] = __builtin_amdgcn_mfma_f32_16x16x32_bf16(bfr[ni], af[mi], acc[mi][ni], 0, 0, 0);
    }

    // epilogue: row = m0+wm+mi*16+lr, cols = n0+wn+ni*16+quad*4 .. +3
#pragma unroll
    for (int mi = 0; mi < 4; ++mi) {
        int row = m0 + wm + mi * 16 + lr;
#pragma unroll
        for (int ni = 0; ni < 2; ++ni) {
            int col = n0 + wn + ni * 16 + quad * 4;
            size_t idx = (size_t)row * N + col;
            f32x4 v = acc[mi][ni];
            if (bias) {
                const float4 b4 = *(const float4*)&bias[col];
                v[0] += b4.x; v[1] += b4.y; v[2] += b4.z; v[3] += b4.w;
            }
            if (act == 1) {
#pragma unroll
                for (int e = 0; e < 4; ++e) {
                    // tanh-approx gelu (max dev ~3e-4 vs exact; vanishes through next GEMM)
                    float xv = v[e];
                    float u = 0.7978845608f * (xv + 0.044715f * xv * xv * xv);
                    float ex = __expf(2.f * u);
                    float th = (ex - 1.f) / (ex + 1.f);
                    v[e] = 0.5f * xv * (1.f + th);
                }
            }
            if (add) {
                const float4 a4 = *(const float4*)&add[idx];
                v[0] += a4.x; v[1] += a4.y; v[2] += a4.z; v[3] += a4.w;
            }
            if (outH) {
                union { __hip_bfloat16 h[4]; int2 i2; } u;
                u.h[0] = __float2bfloat16(v[0]);
                u.h[1] = __float2bfloat16(v[1]);
                u.h[2] = __float2bfloat16(v[2]);
                u.h[3] = __float2bfloat16(v[3]);
                *(int2*)&outH[idx] = u.i2;
            } else {
                *(float4*)&outF[idx] = make_float4(v[0], v[1], v[2], v[3]);
            }
        }
    }
}

extern "C" void kernel_launch(void* const* d_in, const int* in_sizes, int n_in,
                              void* d_out, int out_size, void* d_ws, size_t ws_size,
                              hipStream_t stream) {
    const float* x = (const float*)d_in[0];
    const float* gamma1 = (const float*)d_in[1];
    const float* beta1 = (const float*)d_in[2];
    const float* dwc_w = (const float*)d_in[3];
    const float* dwc_b = (const float*)d_in[4];
    const float* gru1_w = (const float*)d_in[5];
    const float* gru1_o = (const float*)d_in[6];
    const float* gru2_w = (const float*)d_in[7];
    const float* gru2_o = (const float*)d_in[8];
    const float* gamma2 = (const float*)d_in[9];
    const float* beta2 = (const float*)d_in[10];
    const float* p1_w = (const float*)d_in[11];
    const float* p1_b = (const float*)d_in[12];
    const float* p2_w = (const float*)d_in[13];
    const float* p2_b = (const float*)d_in[14];
    float* out = (float*)d_out;

    char* ws = (char*)d_ws;
    size_t off = 0;
    auto alloc = [&](size_t b) {
        char* p = ws + off;
        off += (b + 255) & ~(size_t)255;
        return p;
    };
    const size_t M = M_ROWS;
    // ws total ~188 MB
    __hip_bfloat16* hg = (__hip_bfloat16*)alloc(M * 2 * DI * 2);    // 100.7 MB; h2 in-place; later t1
    __hip_bfloat16* hbuf = (__hip_bfloat16*)alloc(M * DI * 2);      // 50.3 MB: LN1-bf16 out, then h1
    __hip_bfloat16* xs = (__hip_bfloat16*)alloc(M * DIM * 2);       // 25.2 MB; later yn
    float* summ = (float*)alloc((size_t)2 * CHUNKS * NB * DI * 4);  // 6.3 MB
    __hip_bfloat16* w1T = (__hip_bfloat16*)alloc((size_t)DIM * 2 * DI * 2);
    __hip_bfloat16* w2T = (__hip_bfloat16*)alloc((size_t)DIM * 2 * DI * 2);
    __hip_bfloat16* ocT = (__hip_bfloat16*)alloc((size_t)DIM * 2 * DI * 2);  // 384 x 1536 = [o1;o2]^T
    __hip_bfloat16* p1T = (__hip_bfloat16*)alloc((size_t)DIM * MLP_DIM * 2);
    __hip_bfloat16* p2T = (__hip_bfloat16*)alloc((size_t)MLP_DIM * DIM * 2);
    __hip_bfloat16* xnb = hbuf;           // LN1 out (bf16); dead after dwconv, before scan1
    float* y = (float*)d_out;             // post-GRU residual; same-idx RMW only
    __hip_bfloat16* yn = xs;              // LN2 out; xs dead after GRU2 input GEMM
    __hip_bfloat16* t1 = hg;              // MLP hidden; hg dead after scan2

    auto tgrid = [](int n) { return dim3((n + 255) / 256); };
    transpose_bf16_kernel<<<tgrid(DIM * 2 * DI), 256, 0, stream>>>(gru1_w, w1T, DIM, 2 * DI, DIM, 0);
    transpose_bf16_kernel<<<tgrid(DIM * 2 * DI), 256, 0, stream>>>(gru2_w, w2T, DIM, 2 * DI, DIM, 0);
    transpose_bf16_kernel<<<tgrid(DI * DIM), 256, 0, stream>>>(gru1_o, ocT, DI, DIM, 2 * DI, 0);
    transpose_bf16_kernel<<<tgrid(DI * DIM), 256, 0, stream>>>(gru2_o, ocT, DI, DIM, 2 * DI, DI);
    transpose_bf16_kernel<<<tgrid(DIM * MLP_DIM), 256, 0, stream>>>(p1_w, p1T, DIM, MLP_DIM, DIM, 0);
    transpose_bf16_kernel<<<tgrid(MLP_DIM * DIM), 256, 0, stream>>>(p2_w, p2T, MLP_DIM, DIM, MLP_DIM, 0);

    ln_kernel<__hip_bfloat16><<<dim3(M / 4), 256, 0, stream>>>(x, gamma1, beta1, xnb);
    dwconv_kernel<<<dim3((int)((M * DIM / 8) / 256)), 256, 0, stream>>>(xnb, dwc_w, dwc_b, xs);

    const int scan_blocks = NB * CHUNKS * DI / 256;  // 3072
    // GRU1: hg = xs @ w1; scan fwd -> h1 (hbuf, stride DI)
    gemm_bt<<<dim3(2 * DI / 128, M / 128), 512, 0, stream>>>(xs, DIM, xs, DIM, DIM, w1T, M, 2 * DI, DIM,
                                                             hg, nullptr, nullptr, nullptr, 0);
    scan_part1<<<dim3(scan_blocks), 256, 0, stream>>>(hg, summ, 0);
    scan_part2<<<dim3(scan_blocks), 256, 0, stream>>>(hg, summ, hbuf, 0, DI);
    // GRU2: hg = xs @ w2; scan bwd -> h2 in-place into hg[:, 0:DI] (stride 2*DI)
    gemm_bt<<<dim3(2 * DI / 128, M / 128), 512, 0, stream>>>(xs, DIM, xs, DIM, DIM, w2T, M, 2 * DI, DIM,
                                                             hg, nullptr, nullptr, nullptr, 0);
    scan_part1<<<dim3(scan_blocks), 256, 0, stream>>>(hg, summ, 1);
    scan_part2<<<dim3(scan_blocks), 256, 0, stream>>>(hg, summ, hg, 1, 2 * DI);

    // merged GRU out: y = [h1 | h2] @ [o1;o2] + x   (K=1536)
    gemm_bt<<<dim3(DIM / 128, M / 128), 512, 0, stream>>>(hbuf, DI, hg, 2 * DI, DI, ocT, M, DIM, 2 * DI,
                                                          nullptr, y, nullptr, x, 0);

    // LN2 + MLP
    ln_kernel<__hip_bfloat16><<<dim3(M / 4), 256, 0, stream>>>(y, gamma2, beta2, yn);
    gemm_bt<<<dim3(MLP_DIM / 128, M / 128), 512, 0, stream>>>(yn, DIM, yn, DIM, DIM, p1T, M, MLP_DIM, DIM,
                                                              t1, nullptr, p1_b, nullptr, 1);
    gemm_bt<<<dim3(DIM / 128, M / 128), 512, 0, stream>>>(t1, MLP_DIM, t1, MLP_DIM, MLP_DIM, p2T, M, DIM, MLP_DIM,
                                                          nullptr, out, p2_b, y, 0);
}

// Round 10
// 669.630 us; speedup vs baseline: 1.0951x; 1.0194x over previous
//
#include <hip/hip_runtime.h>
#include <hip/hip_bf16.h>

#define DIM 384
#define DI 768
#define S_LEN 1024
#define NB 32
#define M_ROWS (NB * S_LEN)   // 32768
#define MLP_DIM 1536
#define CHUNKS 32
#define CLEN (S_LEN / CHUNKS)  // 32

typedef __bf16 bf16x8 __attribute__((ext_vector_type(8)));
typedef float f32x4 __attribute__((ext_vector_type(4)));

#define GLOBAL_AS __attribute__((address_space(1)))
#define LDS_AS __attribute__((address_space(3)))

// ---------------- LayerNorm: one wave per row of 384 ----------------
template <typename OutT>
__global__ __launch_bounds__(256) void ln_kernel(const float* __restrict__ x,
                                                 const float* __restrict__ gamma,
                                                 const float* __restrict__ beta,
                                                 OutT* __restrict__ out) {
    int row = blockIdx.x * 4 + (threadIdx.x >> 6);
    int lane = threadIdx.x & 63;
    const float* xr = x + (size_t)row * DIM;
    float v[6];
    float s = 0.f, sq = 0.f;
#pragma unroll
    for (int i = 0; i < 6; ++i) {
        v[i] = xr[lane + i * 64];
        s += v[i];
        sq += v[i] * v[i];
    }
#pragma unroll
    for (int off = 32; off > 0; off >>= 1) {
        s += __shfl_down(s, off);
        sq += __shfl_down(sq, off);
    }
    s = __shfl(s, 0);
    sq = __shfl(sq, 0);
    float mean = s * (1.f / DIM);
    float var = sq * (1.f / DIM) - mean * mean;
    float rstd = rsqrtf(var + 1e-5f);
    OutT* orow = out + (size_t)row * DIM;
#pragma unroll
    for (int i = 0; i < 6; ++i) {
        int c = lane + i * 64;
        float y = (v[i] - mean) * rstd * gamma[c] + beta[c];
        if constexpr (sizeof(OutT) == 2)
            orow[c] = __float2bfloat16(y);
        else
            orow[c] = y;
    }
}

// ------- Depthwise 3x3 conv, vectorized: each thread does 8 consecutive channels -------
__global__ __launch_bounds__(256) void dwconv_kernel(const __hip_bfloat16* __restrict__ xn,
                                                     const float* __restrict__ w,
                                                     const float* __restrict__ b,
                                                     __hip_bfloat16* __restrict__ xs) {
    const int CB = DIM / 8;  // 48 channel-blocks per position
    size_t tid = (size_t)blockIdx.x * 256 + threadIdx.x;
    int cb = (int)(tid % CB);
    int s = (int)((tid / CB) % S_LEN);
    int n = (int)(tid / ((size_t)CB * S_LEN));
    int c = cb * 8;
    int h0 = s >> 5, w0 = s & 31;

    float wv[72];
    {
        const float4* wp = (const float4*)(w + (size_t)c * 9);
#pragma unroll
        for (int i = 0; i < 18; ++i) ((float4*)wv)[i] = wp[i];
    }
    float acc[8];
    {
        const float4 b0 = *(const float4*)&b[c];
        const float4 b1 = *(const float4*)&b[c + 4];
        acc[0] = b0.x; acc[1] = b0.y; acc[2] = b0.z; acc[3] = b0.w;
        acc[4] = b1.x; acc[5] = b1.y; acc[6] = b1.z; acc[7] = b1.w;
    }

    const __hip_bfloat16* base = xn + (size_t)n * S_LEN * DIM + c;
#pragma unroll
    for (int kh = 0; kh < 3; ++kh) {
        int hh = h0 + kh - 1;
        if (hh < 0 || hh > 31) continue;
#pragma unroll
        for (int kw = 0; kw < 3; ++kw) {
            int ww = w0 + kw - 1;
            if (ww < 0 || ww > 31) continue;
            bf16x8 xv = *(const bf16x8*)&base[(size_t)(hh * 32 + ww) * DIM];
#pragma unroll
            for (int e = 0; e < 8; ++e)
                acc[e] += (float)xv[e] * wv[e * 9 + kh * 3 + kw];
        }
    }
    bf16x8 ov;
#pragma unroll
    for (int e = 0; e < 8; ++e) ov[e] = (__bf16)acc[e];
    *(bf16x8*)&xs[tid * 8] = ov;
}

// ------- transpose + cast f32 -> bf16: out[c*ostride + ooff + r] = in[r*C + c] -------
__global__ __launch_bounds__(256) void transpose_bf16_kernel(const float* __restrict__ in,
                                                             __hip_bfloat16* __restrict__ out,
                                                             int R, int C, int ostride, int ooff) {
    int idx = blockIdx.x * 256 + threadIdx.x;
    if (idx >= R * C) return;
    int r = idx / C, c = idx % C;
    out[(size_t)c * ostride + ooff + r] = __float2bfloat16(in[idx]);
}

// ---------------- minGRU chunked scan (scalar form: high TLP, 3072 blocks) ----------------
// Rounds 5/8 lessons: vec8 (384 blocks) lost 57us, vec2 (1536 blocks) lost ~20us.
// The scan is a latency-bound dependent chain; thread-count IS the latency hiding.
__device__ __forceinline__ void gru_ab(float hid, float gate, float& a, float& bv) {
    float z = 1.f / (1.f + __expf(-gate));
    float gh = (hid >= 0.f) ? (hid + 0.5f) : (1.f / (1.f + __expf(-hid)));
    a = 1.f - z;
    bv = z * gh;
}

__global__ __launch_bounds__(256) void scan_part1(const __hip_bfloat16* __restrict__ hg,
                                                  float* __restrict__ summ, int rev) {
    int tid = blockIdx.x * 256 + threadIdx.x;  // NB*CHUNKS*DI
    int c = tid % DI;
    int j = (tid / DI) % CHUNKS;
    int b = tid / (DI * CHUNKS);
    const __hip_bfloat16* base = hg + (size_t)b * S_LEN * (2 * DI);
    float A = 1.f, Bv = 0.f;
    for (int i = 0; i < CLEN; i += 8) {
        float hid[8], gate[8];
#pragma unroll
        for (int q = 0; q < 8; ++q) {
            int pos = j * CLEN + i + q;
            int t = rev ? (S_LEN - 1 - pos) : pos;
            hid[q] = __bfloat162float(base[(size_t)t * (2 * DI) + c]);
            gate[q] = __bfloat162float(base[(size_t)t * (2 * DI) + DI + c]);
        }
#pragma unroll
        for (int q = 0; q < 8; ++q) {
            float a, bv;
            gru_ab(hid[q], gate[q], a, bv);
            A *= a;
            Bv = a * Bv + bv;
        }
    }
    int idx = (j * NB + b) * DI + c;
    summ[idx] = A;
    summ[(size_t)CHUNKS * NB * DI + idx] = Bv;
}

// part2: writes h with row stride `ostride`; may alias hg in-place (1:1 read-before-write)
__global__ __launch_bounds__(256) void scan_part2(const __hip_bfloat16* __restrict__ hg,
                                                  const float* __restrict__ summ,
                                                  __hip_bfloat16* __restrict__ ho, int rev,
                                                  int ostride) {
    int tid = blockIdx.x * 256 + threadIdx.x;
    int c = tid % DI;
    int j = (tid / DI) % CHUNKS;
    int b = tid / (DI * CHUNKS);
    const float* sB = summ + (size_t)CHUNKS * NB * DI;
    float h = 0.f;
    for (int jp = 0; jp < j; ++jp) {
        int idx = (jp * NB + b) * DI + c;
        h = summ[idx] * h + sB[idx];
    }
    const __hip_bfloat16* base = hg + (size_t)b * S_LEN * (2 * DI);
    __hip_bfloat16* hob = ho + (size_t)b * S_LEN * ostride;
    for (int i = 0; i < CLEN; i += 8) {
        float hid[8], gate[8];
        int tt[8];
#pragma unroll
        for (int q = 0; q < 8; ++q) {
            int pos = j * CLEN + i + q;
            int t = rev ? (S_LEN - 1 - pos) : pos;
            tt[q] = t;
            hid[q] = __bfloat162float(base[(size_t)t * (2 * DI) + c]);
            gate[q] = __bfloat162float(base[(size_t)t * (2 * DI) + DI + c]);
        }
#pragma unroll
        for (int q = 0; q < 8; ++q) {
            float a, bv;
            gru_ab(hid[q], gate[q], a, bv);
            h = a * h + bv;
            hob[(size_t)tt[q] * ostride + c] = __float2bfloat16(h);
        }
    }
}

// ------- bf16 MFMA GEMM: r9 schedule (8-wave, 85.5us), unroll-3 + running pointers -------
// Round 10: identical schedule/geometry to r9 (3 bufs, depth-2, single barrier/iter,
// counted vmcnt(2), 512 thr / 8 waves per 128x128 tile, T2+XCD swizzles). Change is
// pure VALU reduction (VALUBusy was 60%, 3x MfmaUtil):
//  - loop unrolled by the buffer period (3): bi compile-time -> ds_read addrs become
//    base VGPR + 16-bit imm (bi*8192 + mi*1024), LDS dests fold to constants.
//  - staging uses running per-thread pointers advanced 64B per staged tile, with a
//    branchless uniform reset psA=pA2 at the A1->A2 boundary (KST%3==0 for all calls,
//    so the boundary aligns; reset checked per stage).
// KT in {12,48}, KST in {12,24,48}: KT%3==0 always; main loop runs kb=0..KT-6, the
// last 3 kt are peeled with the r9 endgame waits (vmcnt 2,2,0; stage only in the 1st).
// Round-4 contrast: that was FULL unroll in a latency-bound 12-wave regime; this keeps
// a rolled loop (3/15 iters) in a 24-wave pipe-contention regime.
__global__ __launch_bounds__(512, 6) void gemm_bt(const __hip_bfloat16* __restrict__ A1, int lda1,
                                                  const __hip_bfloat16* __restrict__ A2, int lda2,
                                                  int ksplit,
                                                  const __hip_bfloat16* __restrict__ Bt,
                                                  int M, int N, int K,
                                                  __hip_bfloat16* __restrict__ outH,
                                                  float* __restrict__ outF,
                                                  const float* __restrict__ bias,
                                                  const float* __restrict__ add,
                                                  int act) {
    __shared__ __align__(16) __hip_bfloat16 sA[3][128 * 32];
    __shared__ __align__(16) __hip_bfloat16 sB[3][128 * 32];
    int t = threadIdx.x;

    int nwg = gridDim.x * gridDim.y;
    int bid = blockIdx.y * gridDim.x + blockIdx.x;
    int cpx = nwg >> 3;  // all gemm grids here are divisible by 8 (bijective)
    int tile = (bid & 7) * cpx + (bid >> 3);
    int bx = tile % gridDim.x;
    int by = tile / gridDim.x;
    int n0 = bx * 128;
    int m0 = by * 128;

    int wave = t >> 6, lane = t & 63;
    int wm = (wave >> 2) << 6;  // 0 or 64
    int wn = (wave & 3) << 5;   // 0, 32, 64, 96
    int quad = lane >> 4, lr = lane & 15;

    f32x4 acc[4][2];
#pragma unroll
    for (int i = 0; i < 4; ++i)
#pragma unroll
        for (int j = 0; j < 2; ++j)
#pragma unroll
            for (int e = 0; e < 4; ++e) acc[i][j][e] = 0.f;

    // staging: each buffer = 512 16B chunks (128 rows x 4 slots); thread t owns chunk t.
    // T2 swizzle on the global source slot: LDS (row r, slot s) holds global slot s^f(r),
    // f(r) = (r>>1)&3 (verified: SQ_LDS_BANK_CONFLICT = 0).
    int r0 = t >> 2, g0 = (((t & 3) ^ ((r0 >> 1) & 3)) * 8);
    // read-side swizzle offset (loop-invariant): element offset (quad ^ (lr>>1)&3)*8
    int qx = (quad ^ ((lr >> 1) & 3)) * 8;

    const int KT = K >> 5;        // 12 or 48 (always %3 == 0)
    const int KST = ksplit >> 5;  // 12 / 24 / 48 (always %3 == 0, boundary block-aligned)

    // running per-thread staging sources; advance 64B per staged tile
    const __hip_bfloat16* psA = A1 + (size_t)(m0 + r0) * lda1 + g0;
    const __hip_bfloat16* pA2 = A2 + (size_t)(m0 + r0) * lda2 + g0;
    const __hip_bfloat16* psB = Bt + (size_t)(n0 + r0) * K + g0;
    int kts = 0;  // index of next tile to stage

    auto stageN = [&](int bi) {
        psA = (kts == KST) ? pA2 : psA;  // branchless uniform reset at the A1->A2 boundary
        __builtin_amdgcn_global_load_lds((const GLOBAL_AS void*)psA,
                                         (LDS_AS void*)&sA[bi][t * 8], 16, 0, 0);
        __builtin_amdgcn_global_load_lds((const GLOBAL_AS void*)psB,
                                         (LDS_AS void*)&sB[bi][t * 8], 16, 0, 0);
        psA += 32;
        psB += 32;
        ++kts;
    };

// body for iter using buffer BI (compile-time): [vmcnt(VM); barrier; ds_read; stage; MFMA]
// WAR: stage overwrites buf[(BI+2)%3] = buf[kt-1]; barrier release implies all waves'
// buf[kt-1] reads drained. RAW: vmcnt(2) retires tile kt's 2 loads, keeps kt+1 in flight.
#define GEMM_BODY(BI, VM, DO_STAGE)                                                  \
    {                                                                                \
        asm volatile("s_waitcnt vmcnt(" #VM ")" ::: "memory");                       \
        __builtin_amdgcn_s_barrier();                                                \
        asm volatile("" ::: "memory");                                               \
        bf16x8 af[4], bfr[2];                                                        \
        _Pragma("unroll") for (int mi = 0; mi < 4; ++mi)                             \
            af[mi] = *(const bf16x8*)&sA[BI][(wm + mi * 16 + lr) * 32 + qx];         \
        _Pragma("unroll") for (int ni = 0; ni < 2; ++ni)                             \
            bfr[ni] = *(const bf16x8*)&sB[BI][(wn + ni * 16 + lr) * 32 + qx];        \
        if (DO_STAGE) stageN((BI + 2) % 3);                                          \
        _Pragma("unroll") for (int mi = 0; mi < 4; ++mi)                             \
            _Pragma("unroll") for (int ni = 0; ni < 2; ++ni)                         \
                acc[mi][ni] =                                                        \
                    __builtin_amdgcn_mfma_f32_16x16x32_bf16(bfr[ni], af[mi],         \
                                                            acc[mi][ni], 0, 0, 0);  \
    }

    stageN(0);  // tile 0 -> buf 0
    stageN(1);  // tile 1 -> buf 1
    for (int kb = 0; kb + 3 < KT; kb += 3) {  // kb = 0 .. KT-6
        GEMM_BODY(0, 2, true)
        GEMM_BODY(1, 2, true)
        GEMM_BODY(2, 2, true)
    }
    // tail block kb = KT-3 (KT%3==0): stages only tile KT-1; endgame waits as r9
    GEMM_BODY(0, 2, true)
    GEMM_BODY(1, 2, false)
    GEMM_BODY(2, 0, false)
#undef GEMM_BODY

    // epilogue: row = m0+wm+mi*16+lr, cols = n0+wn+ni*16+quad*4 .. +3
#pragma unroll
    for (int mi = 0; mi < 4; ++mi) {
        int row = m0 + wm + mi * 16 + lr;
#pragma unroll
        for (int ni = 0; ni < 2; ++ni) {
            int col = n0 + wn + ni * 16 + quad * 4;
            size_t idx = (size_t)row * N + col;
            f32x4 v = acc[mi][ni];
            if (bias) {
                const float4 b4 = *(const float4*)&bias[col];
                v[0] += b4.x; v[1] += b4.y; v[2] += b4.z; v[3] += b4.w;
            }
            if (act == 1) {
#pragma unroll
                for (int e = 0; e < 4; ++e) {
                    // tanh-approx gelu (max dev ~3e-4 vs exact; vanishes through next GEMM)
                    float xv = v[e];
                    float u = 0.7978845608f * (xv + 0.044715f * xv * xv * xv);
                    float ex = __expf(2.f * u);
                    float th = (ex - 1.f) / (ex + 1.f);
                    v[e] = 0.5f * xv * (1.f + th);
                }
            }
            if (add) {
                const float4 a4 = *(const float4*)&add[idx];
                v[0] += a4.x; v[1] += a4.y; v[2] += a4.z; v[3] += a4.w;
            }
            if (outH) {
                union { __hip_bfloat16 h[4]; int2 i2; } u;
                u.h[0] = __float2bfloat16(v[0]);
                u.h[1] = __float2bfloat16(v[1]);
                u.h[2] = __float2bfloat16(v[2]);
                u.h[3] = __float2bfloat16(v[3]);
                *(int2*)&outH[idx] = u.i2;
            } else {
                *(float4*)&outF[idx] = make_float4(v[0], v[1], v[2], v[3]);
            }
        }
    }
}

extern "C" void kernel_launch(void* const* d_in, const int* in_sizes, int n_in,
                              void* d_out, int out_size, void* d_ws, size_t ws_size,
                              hipStream_t stream) {
    const float* x = (const float*)d_in[0];
    const float* gamma1 = (const float*)d_in[1];
    const float* beta1 = (const float*)d_in[2];
    const float* dwc_w = (const float*)d_in[3];
    const float* dwc_b = (const float*)d_in[4];
    const float* gru1_w = (const float*)d_in[5];
    const float* gru1_o = (const float*)d_in[6];
    const float* gru2_w = (const float*)d_in[7];
    const float* gru2_o = (const float*)d_in[8];
    const float* gamma2 = (const float*)d_in[9];
    const float* beta2 = (const float*)d_in[10];
    const float* p1_w = (const float*)d_in[11];
    const float* p1_b = (const float*)d_in[12];
    const float* p2_w = (const float*)d_in[13];
    const float* p2_b = (const float*)d_in[14];
    float* out = (float*)d_out;

    char* ws = (char*)d_ws;
    size_t off = 0;
    auto alloc = [&](size_t b) {
        char* p = ws + off;
        off += (b + 255) & ~(size_t)255;
        return p;
    };
    const size_t M = M_ROWS;
    // ws total ~188 MB
    __hip_bfloat16* hg = (__hip_bfloat16*)alloc(M * 2 * DI * 2);    // 100.7 MB; h2 in-place; later t1
    __hip_bfloat16* hbuf = (__hip_bfloat16*)alloc(M * DI * 2);      // 50.3 MB: LN1-bf16 out, then h1
    __hip_bfloat16* xs = (__hip_bfloat16*)alloc(M * DIM * 2);       // 25.2 MB; later yn
    float* summ = (float*)alloc((size_t)2 * CHUNKS * NB * DI * 4);  // 6.3 MB
    __hip_bfloat16* w1T = (__hip_bfloat16*)alloc((size_t)DIM * 2 * DI * 2);
    __hip_bfloat16* w2T = (__hip_bfloat16*)alloc((size_t)DIM * 2 * DI * 2);
    __hip_bfloat16* ocT = (__hip_bfloat16*)alloc((size_t)DIM * 2 * DI * 2);  // 384 x 1536 = [o1;o2]^T
    __hip_bfloat16* p1T = (__hip_bfloat16*)alloc((size_t)DIM * MLP_DIM * 2);
    __hip_bfloat16* p2T = (__hip_bfloat16*)alloc((size_t)MLP_DIM * DIM * 2);
    __hip_bfloat16* xnb = hbuf;           // LN1 out (bf16); dead after dwconv, before scan1
    float* y = (float*)d_out;             // post-GRU residual; same-idx RMW only
    __hip_bfloat16* yn = xs;              // LN2 out; xs dead after GRU2 input GEMM
    __hip_bfloat16* t1 = hg;              // MLP hidden; hg dead after scan2

    auto tgrid = [](int n) { return dim3((n + 255) / 256); };
    transpose_bf16_kernel<<<tgrid(DIM * 2 * DI), 256, 0, stream>>>(gru1_w, w1T, DIM, 2 * DI, DIM, 0);
    transpose_bf16_kernel<<<tgrid(DIM * 2 * DI), 256, 0, stream>>>(gru2_w, w2T, DIM, 2 * DI, DIM, 0);
    transpose_bf16_kernel<<<tgrid(DI * DIM), 256, 0, stream>>>(gru1_o, ocT, DI, DIM, 2 * DI, 0);
    transpose_bf16_kernel<<<tgrid(DI * DIM), 256, 0, stream>>>(gru2_o, ocT, DI, DIM, 2 * DI, DI);
    transpose_bf16_kernel<<<tgrid(DIM * MLP_DIM), 256, 0, stream>>>(p1_w, p1T, DIM, MLP_DIM, DIM, 0);
    transpose_bf16_kernel<<<tgrid(MLP_DIM * DIM), 256, 0, stream>>>(p2_w, p2T, MLP_DIM, DIM, MLP_DIM, 0);

    ln_kernel<__hip_bfloat16><<<dim3(M / 4), 256, 0, stream>>>(x, gamma1, beta1, xnb);
    dwconv_kernel<<<dim3((int)((M * DIM / 8) / 256)), 256, 0, stream>>>(xnb, dwc_w, dwc_b, xs);

    const int scan_blocks = NB * CHUNKS * DI / 256;  // 3072
    // GRU1: hg = xs @ w1; scan fwd -> h1 (hbuf, stride DI)
    gemm_bt<<<dim3(2 * DI / 128, M / 128), 512, 0, stream>>>(xs, DIM, xs, DIM, DIM, w1T, M, 2 * DI, DIM,
                                                             hg, nullptr, nullptr, nullptr, 0);
    scan_part1<<<dim3(scan_blocks), 256, 0, stream>>>(hg, summ, 0);
    scan_part2<<<dim3(scan_blocks), 256, 0, stream>>>(hg, summ, hbuf, 0, DI);
    // GRU2: hg = xs @ w2; scan bwd -> h2 in-place into hg[:, 0:DI] (stride 2*DI)
    gemm_bt<<<dim3(2 * DI / 128, M / 128), 512, 0, stream>>>(xs, DIM, xs, DIM, DIM, w2T, M, 2 * DI, DIM,
                                                             hg, nullptr, nullptr, nullptr, 0);
    scan_part1<<<dim3(scan_blocks), 256, 0, stream>>>(hg, summ, 1);
    scan_part2<<<dim3(scan_blocks), 256, 0, stream>>>(hg, summ, hg, 1, 2 * DI);

    // merged GRU out: y = [h1 | h2] @ [o1;o2] + x   (K=1536, ksplit=768)
    gemm_bt<<<dim3(DIM / 128, M / 128), 512, 0, stream>>>(hbuf, DI, hg, 2 * DI, DI, ocT, M, DIM, 2 * DI,
                                                          nullptr, y, nullptr, x, 0);

    // LN2 + MLP
    ln_kernel<__hip_bfloat16><<<dim3(M / 4), 256, 0, stream>>>(y, gamma2, beta2, yn);
    gemm_bt<<<dim3(MLP_DIM / 128, M / 128), 512, 0, stream>>>(yn, DIM, yn, DIM, DIM, p1T, M, MLP_DIM, DIM,
                                                              t1, nullptr, p1_b, nullptr, 1);
    gemm_bt<<<dim3(DIM / 128, M / 128), 512, 0, stream>>>(t1, MLP_DIM, t1, MLP_DIM, MLP_DIM, p2T, M, DIM, MLP_DIM,
                                                          nullptr, out, p2_b, y, 0);
}